// Round 1
// baseline (360.294 us; speedup 1.0000x reference)
//
#include <hip/hip_runtime.h>
#include <hip/hip_bf16.h>

typedef __hip_bfloat16 bf16;
typedef short frag8 __attribute__((ext_vector_type(8)));   // 8 bf16 = 4 VGPRs
typedef float f32x4 __attribute__((ext_vector_type(4)));

typedef __attribute__((address_space(3))) void lds_void;
typedef __attribute__((address_space(1))) const void gbl_void;

__device__ __forceinline__ void gld16(const void* g, void* l) {
  __builtin_amdgcn_global_load_lds((gbl_void*)g, (lds_void*)l, 16, 0, 0);
}

__device__ __forceinline__ unsigned short f2bf(float f) {
  union { float f; unsigned u; } x; x.f = f;
  unsigned r = x.u + 0x7FFFu + ((x.u >> 16) & 1u);
  return (unsigned short)(r >> 16);
}

// ---------------------------------------------------------------- convert
__global__ __launch_bounds__(256) void cvt_bf16(const float4* __restrict__ s,
                                                ushort4* __restrict__ d, int n4) {
  int i = blockIdx.x * 256 + threadIdx.x;
  if (i >= n4) return;
  float4 v = s[i];
  ushort4 o;
  o.x = f2bf(v.x); o.y = f2bf(v.y); o.z = f2bf(v.z); o.w = f2bf(v.w);
  d[i] = o;
}

// ---------------------------------------------------------------- GEMM  C[M,N] = A[M,K] * W[N,K]^T + bias
// M=4096, N=1024, K=1024. 128x128 tile, 4 waves (2x2), each wave 4x4 16x16x32 MFMA tiles.
// MODE 0: fp32 out, row-major.  MODE 1: QKV fused (z=0,1 -> [b,h,s,d] bf16; z=2 -> [b,h,d,s] bf16)
template<int MODE>
__global__ __launch_bounds__(256)
void gemm_bt(const bf16* __restrict__ A0, const bf16* __restrict__ A1, const bf16* __restrict__ A2,
             const bf16* __restrict__ W0, const bf16* __restrict__ W1, const bf16* __restrict__ W2,
             const float* __restrict__ b0, const float* __restrict__ b1, const float* __restrict__ b2,
             void* __restrict__ o0, void* __restrict__ o1, void* __restrict__ o2) {
  constexpr int NK = 1024;
  __shared__ __align__(16) bf16 As[128 * 64];
  __shared__ __align__(16) bf16 Bs[128 * 64];
  const int tid = threadIdx.x;
  const int wave = tid >> 6, lane = tid & 63, quad = lane >> 4, l16 = lane & 15;
  const int wm = wave >> 1, wn = wave & 1;
  const int bn = blockIdx.x, bm = blockIdx.y;

  const bf16* A = A0; const bf16* W = W0; const float* bias = b0; void* out = o0;
  int z = 0;
  if constexpr (MODE == 1) {
    z = blockIdx.z;
    if (z == 1) { A = A1; W = W1; bias = b1; out = o1; }
    else if (z == 2) { A = A2; W = W2; bias = b2; out = o2; }
  }

  f32x4 acc[4][4];
  #pragma unroll
  for (int i = 0; i < 4; ++i)
    #pragma unroll
    for (int j = 0; j < 4; ++j)
      acc[i][j] = (f32x4){0.f, 0.f, 0.f, 0.f};

  const bf16* Ab = A + (size_t)bm * 128 * NK;
  const bf16* Wb = W + (size_t)bn * 128 * NK;
  const int slot = wave * 64 + lane;
  const int r0 = slot >> 3, c0 = slot & 7;     // 8 chunks of 16B per 64-elem row

  for (int k0 = 0; k0 < NK; k0 += 64) {
    #pragma unroll
    for (int is = 0; is < 4; ++is) {
      const int r = r0 + is * 32;
      gld16(Ab + (size_t)r * NK + k0 + c0 * 8, (void*)(As + (size_t)(is * 256 + wave * 64) * 8));
      gld16(Wb + (size_t)r * NK + k0 + c0 * 8, (void*)(Bs + (size_t)(is * 256 + wave * 64) * 8));
    }
    __syncthreads();
    #pragma unroll
    for (int ks = 0; ks < 2; ++ks) {
      frag8 af[4], bfr[4];
      #pragma unroll
      for (int i = 0; i < 4; ++i)
        af[i] = *(const frag8*)&As[(wm * 64 + i * 16 + l16) * 64 + ks * 32 + quad * 8];
      #pragma unroll
      for (int j = 0; j < 4; ++j)
        bfr[j] = *(const frag8*)&Bs[(wn * 64 + j * 16 + l16) * 64 + ks * 32 + quad * 8];
      #pragma unroll
      for (int i = 0; i < 4; ++i)
        #pragma unroll
        for (int j = 0; j < 4; ++j)
          acc[i][j] = __builtin_amdgcn_mfma_f32_16x16x32_bf16(af[i], bfr[j], acc[i][j], 0, 0, 0);
    }
    __syncthreads();
  }

  // epilogue: C/D layout col = lane&15, row = quad*4 + reg  (m89/m91 verified)
  #pragma unroll
  for (int j = 0; j < 4; ++j) {
    const int col = bn * 128 + wn * 64 + j * 16 + l16;
    const float bv = bias[col];
    #pragma unroll
    for (int i = 0; i < 4; ++i) {
      #pragma unroll
      for (int r = 0; r < 4; ++r) {
        const int row = bm * 128 + wm * 64 + i * 16 + quad * 4 + r;
        const float v = acc[i][j][r] + bv;
        if constexpr (MODE == 0) {
          ((float*)out)[(size_t)row * 1024 + col] = v;
        } else {
          const int b = row >> 11, s = row & 2047;
          const int hh = col >> 6, d = col & 63;
          const bf16 v16 = __float2bfloat16(v);
          if (z < 2) ((bf16*)out)[(((size_t)(b * 16 + hh)) * 2048 + s) * 64 + d] = v16;
          else       ((bf16*)out)[(((size_t)(b * 16 + hh)) * 64 + d) * 2048 + s] = v16;
        }
      }
    }
  }
}

// ---------------------------------------------------------------- flash attention
// Q,K: [32 bh][2048][64] bf16.  Vt: [32 bh][64][2048] bf16.  ctx: [4096][1024] bf16.
// Block: 128 q-rows, 4 waves (32 rows each). 32 iterations over 64-wide kv tiles.
__global__ __launch_bounds__(256)
void flash_attn(const bf16* __restrict__ Q, const bf16* __restrict__ K,
                const bf16* __restrict__ Vt, bf16* __restrict__ ctx) {
  __shared__ __align__(16) bf16 Ks[64 * 64];    // [kv][d]
  __shared__ __align__(16) bf16 Vs[64 * 64];    // [d][kv]
  __shared__ __align__(16) bf16 Ps[128 * 72];   // [q][kv] pad to 72 (stride 36 dw -> 2-way, free)
  const int tid = threadIdx.x;
  const int wave = tid >> 6, lane = tid & 63, quad = lane >> 4, l16 = lane & 15;
  const int bh = blockIdx.y, b = bh >> 4, h = bh & 15;
  const int q0 = blockIdx.x * 128;
  const bf16* Qb = Q + (size_t)bh * 2048 * 64;
  const bf16* Kb = K + (size_t)bh * 2048 * 64;
  const bf16* Vb = Vt + (size_t)bh * 64 * 2048;

  // Q fragments (A-layout: m = lane&15, k = quad*8 + j), wave owns rows wave*32..+31
  frag8 qf[2][2];
  #pragma unroll
  for (int i = 0; i < 2; ++i)
    #pragma unroll
    for (int ks = 0; ks < 2; ++ks)
      qf[i][ks] = *(const frag8*)(Qb + (size_t)(q0 + wave * 32 + i * 16 + l16) * 64 + ks * 32 + quad * 8);

  float m_[2][4], l_[2][4];
  f32x4 o[2][4];
  #pragma unroll
  for (int i = 0; i < 2; ++i)
    #pragma unroll
    for (int r = 0; r < 4; ++r) {
      m_[i][r] = -3.0e38f; l_[i][r] = 0.f;
    }
  #pragma unroll
  for (int i = 0; i < 2; ++i)
    #pragma unroll
    for (int dt = 0; dt < 4; ++dt)
      o[i][dt] = (f32x4){0.f, 0.f, 0.f, 0.f};

  const float SC = 0.0450842200278f;  // log2(e) / sqrt(1024)

  const int slot = wave * 64 + lane;
  const int r0 = slot >> 3, c0 = slot & 7;

  for (int kt = 0; kt < 32; ++kt) {
    #pragma unroll
    for (int is = 0; is < 2; ++is) {
      const int r = r0 + is * 32;
      gld16(Kb + (size_t)(kt * 64 + r) * 64 + c0 * 8, (void*)(Ks + (size_t)(is * 256 + wave * 64) * 8));
      gld16(Vb + (size_t)r * 2048 + kt * 64 + c0 * 8, (void*)(Vs + (size_t)(is * 256 + wave * 64) * 8));
    }
    __syncthreads();

    // S = Q * K^T  (raw, unscaled)
    f32x4 s[2][4];
    #pragma unroll
    for (int i = 0; i < 2; ++i)
      #pragma unroll
      for (int j = 0; j < 4; ++j)
        s[i][j] = (f32x4){0.f, 0.f, 0.f, 0.f};
    #pragma unroll
    for (int ks = 0; ks < 2; ++ks) {
      frag8 kf[4];
      #pragma unroll
      for (int j = 0; j < 4; ++j)
        kf[j] = *(const frag8*)&Ks[(j * 16 + l16) * 64 + ks * 32 + quad * 8];
      #pragma unroll
      for (int i = 0; i < 2; ++i)
        #pragma unroll
        for (int j = 0; j < 4; ++j)
          s[i][j] = __builtin_amdgcn_mfma_f32_16x16x32_bf16(qf[i][ks], kf[j], s[i][j], 0, 0, 0);
    }

    // online softmax: row = i*16 + quad*4 + r, cols spread over 16 lanes x 4 tiles
    #pragma unroll
    for (int i = 0; i < 2; ++i)
      #pragma unroll
      for (int r = 0; r < 4; ++r) {
        float mx = fmaxf(fmaxf(s[i][0][r], s[i][1][r]), fmaxf(s[i][2][r], s[i][3][r]));
        #pragma unroll
        for (int msk = 1; msk < 16; msk <<= 1) mx = fmaxf(mx, __shfl_xor(mx, msk, 64));
        const float mn = fmaxf(m_[i][r], mx);
        const float al = exp2f((m_[i][r] - mn) * SC);
        m_[i][r] = mn;
        float rs = 0.f;
        #pragma unroll
        for (int j = 0; j < 4; ++j) {
          const float p = exp2f((s[i][j][r] - mn) * SC);
          s[i][j][r] = p; rs += p;
        }
        #pragma unroll
        for (int msk = 1; msk < 16; msk <<= 1) rs += __shfl_xor(rs, msk, 64);
        l_[i][r] = l_[i][r] * al + rs;
        #pragma unroll
        for (int dt = 0; dt < 4; ++dt) o[i][dt][r] = o[i][dt][r] * al;
      }

    // P (C-layout) -> LDS row-major, for A-layout re-read
    #pragma unroll
    for (int i = 0; i < 2; ++i)
      #pragma unroll
      for (int j = 0; j < 4; ++j)
        #pragma unroll
        for (int r = 0; r < 4; ++r) {
          const int row = wave * 32 + i * 16 + quad * 4 + r;
          Ps[row * 72 + j * 16 + l16] = __float2bfloat16(s[i][j][r]);
        }
    __syncthreads();

    // O += P * V   (B-frags from Vt tile: contiguous kv per lane)
    #pragma unroll
    for (int ks = 0; ks < 2; ++ks) {
      frag8 pf[2], vf[4];
      #pragma unroll
      for (int i = 0; i < 2; ++i)
        pf[i] = *(const frag8*)&Ps[(wave * 32 + i * 16 + l16) * 72 + ks * 32 + quad * 8];
      #pragma unroll
      for (int dt = 0; dt < 4; ++dt)
        vf[dt] = *(const frag8*)&Vs[(dt * 16 + l16) * 64 + ks * 32 + quad * 8];
      #pragma unroll
      for (int i = 0; i < 2; ++i)
        #pragma unroll
        for (int dt = 0; dt < 4; ++dt)
          o[i][dt] = __builtin_amdgcn_mfma_f32_16x16x32_bf16(pf[i], vf[dt], o[i][dt], 0, 0, 0);
    }
    __syncthreads();
  }

  // epilogue: ctx[b, q, h*64 + d]
  #pragma unroll
  for (int i = 0; i < 2; ++i)
    #pragma unroll
    for (int dt = 0; dt < 4; ++dt)
      #pragma unroll
      for (int r = 0; r < 4; ++r) {
        const int row = q0 + wave * 32 + i * 16 + quad * 4 + r;
        const int col = h * 64 + dt * 16 + l16;
        const float v = o[i][dt][r] / l_[i][r];
        ctx[((size_t)(b * 2048 + row)) * 1024 + col] = __float2bfloat16(v);
      }
}

// ---------------------------------------------------------------- launch
extern "C" void kernel_launch(void* const* d_in, const int* in_sizes, int n_in,
                              void* d_out, int out_size, void* d_ws, size_t ws_size,
                              hipStream_t stream) {
  const float* q_in = (const float*)d_in[0];
  const float* k_in = (const float*)d_in[1];
  const float* v_in = (const float*)d_in[2];
  const float* Wq = (const float*)d_in[3];
  const float* bq = (const float*)d_in[4];
  const float* Wk = (const float*)d_in[5];
  const float* bk = (const float*)d_in[6];
  const float* Wv = (const float*)d_in[7];
  const float* bv = (const float*)d_in[8];
  const float* Wo = (const float*)d_in[9];
  const float* bo = (const float*)d_in[10];

  char* ws = (char*)d_ws;
  const size_t MB = 1024 * 1024;
  bf16* Xq  = (bf16*)(ws + 0 * MB);    // [4096][1024]
  bf16* Xk  = (bf16*)(ws + 8 * MB);
  bf16* Xv  = (bf16*)(ws + 16 * MB);
  bf16* Wqb = (bf16*)(ws + 24 * MB);   // [1024][1024]
  bf16* Wkb = (bf16*)(ws + 26 * MB);
  bf16* Wvb = (bf16*)(ws + 28 * MB);
  bf16* Wob = (bf16*)(ws + 30 * MB);
  bf16* Qw  = (bf16*)(ws + 32 * MB);   // [32][2048][64]
  bf16* Kw  = (bf16*)(ws + 40 * MB);   // [32][2048][64]
  bf16* Vtw = (bf16*)(ws + 48 * MB);   // [32][64][2048]
  bf16* Ctx = (bf16*)(ws + 56 * MB);   // [4096][1024]   (ends at 64 MB)

  // fp32 -> bf16 conversions
  {
    const int n4a = 4194304 / 4, n4w = 1048576 / 4;
    cvt_bf16<<<dim3((n4a + 255) / 256), 256, 0, stream>>>((const float4*)q_in, (ushort4*)Xq, n4a);
    cvt_bf16<<<dim3((n4a + 255) / 256), 256, 0, stream>>>((const float4*)k_in, (ushort4*)Xk, n4a);
    cvt_bf16<<<dim3((n4a + 255) / 256), 256, 0, stream>>>((const float4*)v_in, (ushort4*)Xv, n4a);
    cvt_bf16<<<dim3((n4w + 255) / 256), 256, 0, stream>>>((const float4*)Wq, (ushort4*)Wqb, n4w);
    cvt_bf16<<<dim3((n4w + 255) / 256), 256, 0, stream>>>((const float4*)Wk, (ushort4*)Wkb, n4w);
    cvt_bf16<<<dim3((n4w + 255) / 256), 256, 0, stream>>>((const float4*)Wv, (ushort4*)Wvb, n4w);
    cvt_bf16<<<dim3((n4w + 255) / 256), 256, 0, stream>>>((const float4*)Wo, (ushort4*)Wob, n4w);
  }

  // fused QKV projection (z: 0=Q, 1=K, 2=V-transposed)
  gemm_bt<1><<<dim3(8, 32, 3), 256, 0, stream>>>(Xq, Xk, Xv, Wqb, Wkb, Wvb,
                                                 bq, bk, bv, Qw, Kw, Vtw);
  // attention
  flash_attn<<<dim3(16, 32), 256, 0, stream>>>(Qw, Kw, Vtw, Ctx);
  // output projection -> fp32 d_out
  gemm_bt<0><<<dim3(8, 32, 1), 256, 0, stream>>>(Ctx, nullptr, nullptr, Wob, nullptr, nullptr,
                                                 bo, nullptr, nullptr, d_out, nullptr, nullptr);
}